// Round 9
// baseline (233.575 us; speedup 1.0000x reference)
//
#include <hip/hip_runtime.h>
#include <stdint.h>

#define DIM   128
#define KCOLS 65536
#define BB    1024
#define LL    512
#define PSZ   8388608
#define INV_T (1.0f / 0.09f)
#define MOM   0.7f
#define CAP   40   // bucket capacity; counts are Poisson(8), P(>=40)~1e-16/bucket

// output layout (float32 elements, concatenated in return order)
#define OUT_LOGITS 0
#define OUT_LABELS (BB * LL)                    // 524288
#define OUT_QUEUE  (BB * LL + BB)               // 525312
#define OUT_PARAMK (BB * LL + BB + DIM * KCOLS) // 8913920

// ws layout (bytes)
#define WS_QT  0                        // bf16 queueT [KCOLS][DIM] = 16 MiB
#define WS_CNT (16777216)               // uint32 cnt[KCOLS] = 256 KiB
#define WS_TAB (WS_CNT + 262144)        // uint32 table[KCOLS][CAP] = 10 MiB
#define WS_QN  (WS_TAB + KCOLS * CAP * 4) // f32 qn[BB][DIM] = 512 KiB

typedef float f32x4 __attribute__((ext_vector_type(4)));

__device__ inline unsigned short f32_to_bf16(float f) {
    uint32_t u = __float_as_uint(f);
    uint32_t r = (u + 0x7fffu + ((u >> 16) & 1u)) >> 16;
    return (unsigned short)r;
}

// k0: zero bucket counters + labels
__global__ void __launch_bounds__(256)
init_kernel(uint32_t* __restrict__ cnt, float* __restrict__ out) {
    int bid = blockIdx.x, t = threadIdx.x;
    if (bid < 64) {
        uint4 z = {0u, 0u, 0u, 0u};
        ((uint4*)cnt)[bid * 256 + t] = z;   // 64*256*4 = 65536 uint32
    } else {
        f32x4 z = {0.f, 0.f, 0.f, 0.f};
        ((f32x4*)(out + OUT_LABELS))[t] = z;
    }
}

// k1: ALL pure-streaming work, 1:1 block-interleaved, plus tail blocks that
// build the inverted index (sidx -> per-column buckets) and normalize q.
//   bid < 2048, odd : param momentum chunk (nontemporal)
//   bid < 2048, even: queue tile (nt read/write; qt CACHEABLE)
//   2048..2303      : scatter sidx into buckets (L2-resident atomics,
//                     hidden under the HBM-saturated stream)
//   2304..2559      : qn = normalize(q) * (1/T), wave-per-row
__global__ void __launch_bounds__(256)
queue_param_kernel(const float* __restrict__ queue,
                   const float* __restrict__ keys,
                   const int* __restrict__ ptr_p,
                   const float* __restrict__ pq,
                   const float* __restrict__ pk,
                   const int* __restrict__ sidx,
                   const float* __restrict__ q,
                   float* __restrict__ out,
                   unsigned short* __restrict__ qt,
                   uint32_t* __restrict__ cnt,
                   uint32_t* __restrict__ table,
                   float* __restrict__ qn) {
    int bid = blockIdx.x;
    int t   = threadIdx.x;

    if (bid >= 2304) {
        // ---- qn path: 256 blocks x 4 rows, wave per row ----
        int w    = t >> 6;
        int lane = t & 63;
        int r    = (bid - 2304) * 4 + w;
        float2 v = *(const float2*)&q[(size_t)r * DIM + lane * 2];
        float s  = v.x * v.x + v.y * v.y;
#pragma unroll
        for (int m = 32; m >= 1; m >>= 1) s += __shfl_xor(s, m, 64);
        float inv = rsqrtf(s) * INV_T;
        float2 o  = {v.x * inv, v.y * inv};
        *(float2*)&qn[(size_t)r * DIM + lane * 2] = o;
        return;
    }
    if (bid >= 2048) {
        // ---- scatter path: 256 blocks x 2048 entries ----
        int i = bid - 2048;
        const int4* s4 = (const int4*)sidx;
#pragma unroll
        for (int c = 0; c < 2; ++c) {
            int chunk = i * 512 + c * 256 + t;    // int4 index
            int4 v = s4[chunk];
            int flat0 = chunk * 4;
            int ids[4] = {v.x, v.y, v.z, v.w};
#pragma unroll
            for (int j = 0; j < 4; ++j) {
                int idx  = ids[j];
                int flat = flat0 + j;
                int b = flat >> 9, l = flat & (LL - 1);
                uint32_t p = atomicAdd(&cnt[idx], 1u);
                if (p < CAP)
                    table[(size_t)idx * CAP + p] =
                        ((uint32_t)b << 16) | (uint32_t)l;
            }
        }
        return;
    }
    if (bid & 1) {
        // ---- param momentum path (nontemporal) ----
        int c = bid >> 1;
        const f32x4* pq4 = (const f32x4*)pq;
        const f32x4* pk4 = (const f32x4*)pk;
        f32x4* paramk4   = (f32x4*)(out + OUT_PARAMK);
#pragma unroll
        for (int i = 0; i < 8; ++i) {
            int gid = c * 2048 + i * 256 + t;
            f32x4 a = __builtin_nontemporal_load(pq4 + gid);
            f32x4 b = __builtin_nontemporal_load(pk4 + gid);
            f32x4 r = b * MOM + a * (1.0f - MOM);
            __builtin_nontemporal_store(r, paramk4 + gid);
        }
        return;
    }

    // ---- queue tile path ----
    __shared__ float tile[64][DIM + 1];  // [k][d], ~33 KB
    __shared__ float invn_s[64];
    int k0 = (bid >> 1) * 64;
    int ptr   = ptr_p[0];
    int start = min(max(ptr, 0), KCOLS - BB);  // dynamic_update_slice clamp

    // cooperative inv-norms for the key rows this block will write (if any)
    {
        int row_local = t >> 2;       // 0..63 -> column k0+row_local
        int l4        = t & 3;        // 32-dim slice
        int c = k0 + row_local;
        if (c >= start && c < start + BB) {
            const float4* kr =
                (const float4*)&keys[(size_t)(c - start) * DIM + l4 * 32];
            float s = 0.f;
#pragma unroll
            for (int i = 0; i < 8; ++i) {
                float4 v = kr[i];
                s += v.x * v.x + v.y * v.y + v.z * v.z + v.w * v.w;
            }
            s += __shfl_xor(s, 1, 64);
            s += __shfl_xor(s, 2, 64);
            if (l4 == 0) invn_s[row_local] = 1.0f / sqrtf(s);
        }
    }
    __syncthreads();

    int lane16 = t & 15;
    int hi     = t >> 4;       // 0..15
    int kq     = lane16 * 4;   // column offset within tile, step 4
#pragma unroll
    for (int p = 0; p < 8; ++p) {
        int d = p * 16 + hi;
        f32x4 v = __builtin_nontemporal_load(
            (const f32x4*)&queue[(size_t)d * KCOLS + k0 + kq]);
        float vv[4] = {v.x, v.y, v.z, v.w};
#pragma unroll
        for (int j = 0; j < 4; ++j) {
            tile[kq + j][d] = vv[j];           // original value for qt
            int col = k0 + kq + j;
            if (col >= start && col < start + BB)
                vv[j] = keys[(size_t)(col - start) * DIM + d] * invn_s[kq + j];
        }
        f32x4 w = {vv[0], vv[1], vv[2], vv[3]};
        __builtin_nontemporal_store(
            w, (f32x4*)&out[OUT_QUEUE + (size_t)d * KCOLS + k0 + kq]);
    }
    __syncthreads();
    // transpose out: each lane packs 8 consecutive d of one k-row -> uint4
    // (cacheable store: qt stays L2/LLC-resident for k2's sequential sweep)
    int d0 = lane16 * 8;
#pragma unroll
    for (int ki = 0; ki < 4; ++ki) {
        int kl = hi + ki * 16;  // 0..63
        float f[8];
#pragma unroll
        for (int j = 0; j < 8; ++j) f[j] = tile[kl][d0 + j];
        uint4 o;
        o.x = (uint32_t)f32_to_bf16(f[0]) | ((uint32_t)f32_to_bf16(f[1]) << 16);
        o.y = (uint32_t)f32_to_bf16(f[2]) | ((uint32_t)f32_to_bf16(f[3]) << 16);
        o.z = (uint32_t)f32_to_bf16(f[4]) | ((uint32_t)f32_to_bf16(f[5]) << 16);
        o.w = (uint32_t)f32_to_bf16(f[6]) | ((uint32_t)f32_to_bf16(f[7]) << 16);
        *(uint4*)&qt[(size_t)(k0 + kl) * DIM + d0] = o;
    }
}

// 8-term bf16 dot-accumulate against a qreg slice
#define DOT8(uu, qo, dst) {                                    \
    float acc = 0.f;                                           \
    acc += qreg[(qo) + 0] * __uint_as_float((uu).x << 16);     \
    acc += qreg[(qo) + 1] * __uint_as_float((uu).x & 0xffff0000u); \
    acc += qreg[(qo) + 2] * __uint_as_float((uu).y << 16);     \
    acc += qreg[(qo) + 3] * __uint_as_float((uu).y & 0xffff0000u); \
    acc += qreg[(qo) + 4] * __uint_as_float((uu).z << 16);     \
    acc += qreg[(qo) + 5] * __uint_as_float((uu).z & 0xffff0000u); \
    acc += qreg[(qo) + 6] * __uint_as_float((uu).w << 16);     \
    acc += qreg[(qo) + 7] * __uint_as_float((uu).w & 0xffff0000u); \
    (dst) = acc; }

// k2: INVERTED logits. Block g owns columns [g*64, g*64+64):
//   - stage its 64 qt rows into LDS (sequential 16 MB sweep chip-wide,
//     read ONCE -- replaces R8's 134 MB LLC gather)
//   - serial-scan the 64 bucket counts into offsets
//   - quartets process bucket entries load-balanced (binary search on
//     offsets); q row comes from qn (512 KB, L2-resident on every XCD)
__global__ void __launch_bounds__(256)
logits_inv_kernel(const float* __restrict__ qn,
                  const unsigned short* __restrict__ qt,
                  const uint32_t* __restrict__ cnt,
                  const uint32_t* __restrict__ table,
                  float* __restrict__ out) {
    __shared__ uint4 ldsc[64 * 17];   // 64 rows x 16 uint4, stride 17 (skew)
    __shared__ int offs[65];
    __shared__ int cl[64];
    int g = blockIdx.x, t = threadIdx.x;
    int K0 = g * 64;

    const uint4* qt4 = (const uint4*)qt;
#pragma unroll
    for (int i = t; i < 1024; i += 256) {
        int row = i >> 4, u = i & 15;
        ldsc[row * 17 + u] = qt4[(size_t)(K0 + row) * 16 + u];
    }
    if (t < 64) cl[t] = min((int)cnt[K0 + t], CAP);
    __syncthreads();
    if (t == 0) {
        int run = 0;
        for (int c = 0; c < 64; ++c) { offs[c] = run; run += cl[c]; }
        offs[64] = run;
    }
    __syncthreads();
    int E = offs[64];

    int quarter = t & 3;
    int qid     = t >> 2;

    for (int e = qid; e < E; e += 64) {
        // find column c: offs[c] <= e < offs[c+1]
        int lo = 0, hi = 64;
#pragma unroll
        for (int it = 0; it < 6; ++it) {
            int mid = (lo + hi) >> 1;
            if (offs[mid] <= e) lo = mid; else hi = mid;
        }
        int c    = lo;
        int slot = e - offs[c];
        uint32_t tab = table[(size_t)(K0 + c) * CAP + slot];
        int b = tab >> 16, l = tab & 0xffff;

        float qreg[32];
        const f32x4* qv4 = (const f32x4*)(qn + (size_t)b * DIM + quarter * 32);
#pragma unroll
        for (int j = 0; j < 8; ++j) {
            f32x4 v = qv4[j];
            qreg[4 * j + 0] = v.x; qreg[4 * j + 1] = v.y;
            qreg[4 * j + 2] = v.z; qreg[4 * j + 3] = v.w;
        }
        const uint4* cp = &ldsc[c * 17 + quarter * 4];
        uint4 u0 = cp[0], u1 = cp[1], u2 = cp[2], u3 = cp[3];
        float s0, s1, s2, s3;
        DOT8(u0,  0, s0);
        DOT8(u1,  8, s1);
        DOT8(u2, 16, s2);
        DOT8(u3, 24, s3);
        float s = (s0 + s1) + (s2 + s3);
        s += __shfl_xor(s, 1, 64);
        s += __shfl_xor(s, 2, 64);
        if (quarter == 0) out[(size_t)b * LL + l] = s;
    }
}

extern "C" void kernel_launch(void* const* d_in, const int* in_sizes, int n_in,
                              void* d_out, int out_size, void* d_ws, size_t ws_size,
                              hipStream_t stream) {
    const float* q     = (const float*)d_in[0];
    const float* queue = (const float*)d_in[1];
    const float* keys  = (const float*)d_in[2];
    const float* pq    = (const float*)d_in[3];
    const float* pk    = (const float*)d_in[4];
    const int*   sidx  = (const int*)d_in[5];
    const int*   ptr_p = (const int*)d_in[6];
    float* out = (float*)d_out;

    unsigned short* ws_qt  = (unsigned short*)((char*)d_ws + WS_QT);
    uint32_t*       ws_cnt = (uint32_t*)((char*)d_ws + WS_CNT);
    uint32_t*       ws_tab = (uint32_t*)((char*)d_ws + WS_TAB);
    float*          ws_qn  = (float*)((char*)d_ws + WS_QN);

    // k0: zero bucket counters + labels
    init_kernel<<<65, 256, 0, stream>>>(ws_cnt, out);
    // k1: streaming (queue transform + param momentum) + inverted-index build
    queue_param_kernel<<<2560, 256, 0, stream>>>(queue, keys, ptr_p, pq, pk,
                                                 sidx, q, out, ws_qt, ws_cnt,
                                                 ws_tab, ws_qn);
    // k2: inverted logits (each qt row read once)
    logits_inv_kernel<<<KCOLS / 64, 256, 0, stream>>>(ws_qn, ws_qt, ws_cnt,
                                                      ws_tab,
                                                      out + OUT_LOGITS);
}

// Round 10
// 177.327 us; speedup vs baseline: 1.3172x; 1.3172x over previous
//
#include <hip/hip_runtime.h>
#include <stdint.h>

#define DIM   128
#define KCOLS 65536
#define BB    1024
#define LL    512
#define PSZ   8388608
#define INV_T (1.0f / 0.09f)
#define MOM   0.7f

// output layout (float32 elements, concatenated in return order)
#define OUT_LOGITS 0
#define OUT_LABELS (BB * LL)                    // 524288
#define OUT_QUEUE  (BB * LL + BB)               // 525312
#define OUT_PARAMK (BB * LL + BB + DIM * KCOLS) // 8913920

// ws layout (bytes)
#define WS_QT 0   // bf16 queueT [KCOLS][DIM] = 16 MiB

typedef float f32x4 __attribute__((ext_vector_type(4)));

__device__ inline unsigned short f32_to_bf16(float f) {
    uint32_t u = __float_as_uint(f);
    uint32_t r = (u + 0x7fffu + ((u >> 16) & 1u)) >> 16;
    return (unsigned short)r;
}

// Kernel 1: ALL pure-streaming work, 1:1 block-interleaved.
//   odd  bid -> param momentum chunk (8 f32x4/thread, nontemporal)
//   even bid -> queue tile: read queue (nt), write new_queue (nt, with
//               inline-normalized key overwrite) + bf16 transposed qt
//               (CACHEABLE -> resident in L2/LLC for kernel 2).
// Both streams are BW-bound and additive (~177 MB / 6.2 TB/s ~= 29 us);
// keeping the HBM-saturating stream out of kernel 2's dispatch window is
// worth ~2 us vs co-residency (R6 vs R8 measured).
__global__ void __launch_bounds__(256)
queue_param_kernel(const float* __restrict__ queue,
                   const float* __restrict__ keys,
                   const int* __restrict__ ptr_p,
                   const float* __restrict__ pq,
                   const float* __restrict__ pk,
                   float* __restrict__ out,
                   unsigned short* __restrict__ qt) {
    int bid = blockIdx.x;
    int t   = threadIdx.x;

    if (bid & 1) {
        // ---- param momentum path (nontemporal; 1024 blocks x 2048 f32x4) --
        int c = bid >> 1;
        const f32x4* pq4 = (const f32x4*)pq;
        const f32x4* pk4 = (const f32x4*)pk;
        f32x4* paramk4   = (f32x4*)(out + OUT_PARAMK);
#pragma unroll
        for (int i = 0; i < 8; ++i) {
            int gid = c * 2048 + i * 256 + t;
            f32x4 a = __builtin_nontemporal_load(pq4 + gid);
            f32x4 b = __builtin_nontemporal_load(pk4 + gid);
            f32x4 r = b * MOM + a * (1.0f - MOM);
            __builtin_nontemporal_store(r, paramk4 + gid);
        }
        if (c == 0) {
            f32x4 z = {0.f, 0.f, 0.f, 0.f};
            ((f32x4*)(out + OUT_LABELS))[t] = z;
        }
        return;
    }

    // ---- queue tile path ----
    __shared__ float tile[64][DIM + 1];  // [k][d], ~33 KB
    __shared__ float invn_s[64];
    int k0 = (bid >> 1) * 64;
    int ptr   = ptr_p[0];
    int start = min(max(ptr, 0), KCOLS - BB);  // dynamic_update_slice clamp

    // cooperative inv-norms for the key rows this block will write (if any)
    {
        int row_local = t >> 2;       // 0..63 -> column k0+row_local
        int l4        = t & 3;        // 32-dim slice
        int c = k0 + row_local;
        if (c >= start && c < start + BB) {
            const float4* kr =
                (const float4*)&keys[(size_t)(c - start) * DIM + l4 * 32];
            float s = 0.f;
#pragma unroll
            for (int i = 0; i < 8; ++i) {
                float4 v = kr[i];
                s += v.x * v.x + v.y * v.y + v.z * v.z + v.w * v.w;
            }
            s += __shfl_xor(s, 1, 64);
            s += __shfl_xor(s, 2, 64);
            if (l4 == 0) invn_s[row_local] = 1.0f / sqrtf(s);
        }
    }
    __syncthreads();

    int lane16 = t & 15;
    int hi     = t >> 4;       // 0..15
    int kq     = lane16 * 4;   // column offset within tile, step 4
#pragma unroll
    for (int p = 0; p < 8; ++p) {
        int d = p * 16 + hi;
        f32x4 v = __builtin_nontemporal_load(
            (const f32x4*)&queue[(size_t)d * KCOLS + k0 + kq]);
        float vv[4] = {v.x, v.y, v.z, v.w};
#pragma unroll
        for (int j = 0; j < 4; ++j) {
            tile[kq + j][d] = vv[j];           // original value for qt
            int col = k0 + kq + j;
            if (col >= start && col < start + BB)
                vv[j] = keys[(size_t)(col - start) * DIM + d] * invn_s[kq + j];
        }
        f32x4 w = {vv[0], vv[1], vv[2], vv[3]};
        __builtin_nontemporal_store(
            w, (f32x4*)&out[OUT_QUEUE + (size_t)d * KCOLS + k0 + kq]);
    }
    __syncthreads();
    // transpose out: each lane packs 8 consecutive d of one k-row -> uint4
    // (cacheable store: qt stays L2/LLC-resident for kernel 2)
    int d0 = lane16 * 8;
#pragma unroll
    for (int ki = 0; ki < 4; ++ki) {
        int kl = hi + ki * 16;  // 0..63
        float f[8];
#pragma unroll
        for (int j = 0; j < 8; ++j) f[j] = tile[kl][d0 + j];
        uint4 o;
        o.x = (uint32_t)f32_to_bf16(f[0]) | ((uint32_t)f32_to_bf16(f[1]) << 16);
        o.y = (uint32_t)f32_to_bf16(f[2]) | ((uint32_t)f32_to_bf16(f[3]) << 16);
        o.z = (uint32_t)f32_to_bf16(f[4]) | ((uint32_t)f32_to_bf16(f[5]) << 16);
        o.w = (uint32_t)f32_to_bf16(f[6]) | ((uint32_t)f32_to_bf16(f[7]) << 16);
        *(uint4*)&qt[(size_t)(k0 + kl) * DIM + d0] = o;
    }
}

// 8-term bf16 dot-accumulate against a qreg slice
#define DOT8(uu, qo, dst) {                                    \
    float acc = 0.f;                                           \
    acc += qreg[(qo) + 0] * __uint_as_float((uu).x << 16);     \
    acc += qreg[(qo) + 1] * __uint_as_float((uu).x & 0xffff0000u); \
    acc += qreg[(qo) + 2] * __uint_as_float((uu).y << 16);     \
    acc += qreg[(qo) + 3] * __uint_as_float((uu).y & 0xffff0000u); \
    acc += qreg[(qo) + 4] * __uint_as_float((uu).z << 16);     \
    acc += qreg[(qo) + 5] * __uint_as_float((uu).z & 0xffff0000u); \
    acc += qreg[(qo) + 6] * __uint_as_float((uu).w << 16);     \
    acc += qreg[(qo) + 7] * __uint_as_float((uu).w & 0xffff0000u); \
    (dst) = acc; }

// Kernel 2: logits ONLY, against a quiet memory system.
// TWO blocks per batch row (2048 blocks, 8/CU): block handles entries
// [half*256, half*256+256) of row b. Same per-lane ILP as R8 (16 x 16B
// loads in flight via the 4-deep window over this quartet's 4 entries),
// but 2x the chip-wide outstanding-miss pool and half the per-block
// critical path (shorter straggler tail).
// Line-coalesced: a quartet's 4 lanes read quarter*16B of ONE 64B segment.
__global__ void __launch_bounds__(256)
logits_kernel(const float* __restrict__ q,
              const unsigned short* __restrict__ qt,
              const int* __restrict__ sidx,
              float* __restrict__ out) {
    int b    = blockIdx.x >> 1;
    int half = blockIdx.x & 1;
    int t    = threadIdx.x;

    __shared__ int sl[256];
    sl[t] = sidx[b * LL + half * 256 + t];

    int quarter = t & 3;   // which 16B piece of each 64B segment
    int grp     = t >> 2;  // 0..63: which l-slot within each pass

    // normalize q[b] in-register; fold 1/T in.
    // Lane holds dims  j*32 + quarter*8 + {0..7}  (slot-major gather layout).
    float qreg[32];
    {
        const float* qb = q + (size_t)b * DIM;
        float s = 0.f;
#pragma unroll
        for (int j = 0; j < 4; ++j) {
            const float4* pp = (const float4*)(qb + j * 32 + quarter * 8);
            float4 v0 = pp[0], v1 = pp[1];
            qreg[j * 8 + 0] = v0.x; qreg[j * 8 + 1] = v0.y;
            qreg[j * 8 + 2] = v0.z; qreg[j * 8 + 3] = v0.w;
            qreg[j * 8 + 4] = v1.x; qreg[j * 8 + 5] = v1.y;
            qreg[j * 8 + 6] = v1.z; qreg[j * 8 + 7] = v1.w;
            s += v0.x * v0.x + v0.y * v0.y + v0.z * v0.z + v0.w * v0.w;
            s += v1.x * v1.x + v1.y * v1.y + v1.z * v1.z + v1.w * v1.w;
        }
        s += __shfl_xor(s, 1, 64);
        s += __shfl_xor(s, 2, 64);
        float inv = rsqrtf(s) * INV_T;
#pragma unroll
        for (int i = 0; i < 32; ++i) qreg[i] *= inv;
    }
    __syncthreads();

    // this quartet's 4 gather indices (LDS broadcast reads)
    int idxs[4];
#pragma unroll
    for (int e = 0; e < 4; ++e) idxs[e] = sl[grp + (e << 6)];

    // all 4 entries prefetched (16 x 16B in flight), then drain.
    // entry e's 256B row read as 4 slot-major uint4s:
    // lane address = idx*256B + j*64B + quarter*16B
    uint4 w[4][4];
#pragma unroll
    for (int e = 0; e < 4; ++e) {
        const uint4* p = (const uint4*)(qt + (size_t)idxs[e] * DIM) + quarter;
        w[e][0] = p[0]; w[e][1] = p[4]; w[e][2] = p[8]; w[e][3] = p[12];
    }
#pragma unroll
    for (int e = 0; e < 4; ++e) {
        uint4 t0 = w[e][0], t1 = w[e][1], t2 = w[e][2], t3 = w[e][3];
        float s0, s1, s2, s3;
        DOT8(t0,  0, s0);
        DOT8(t1,  8, s1);
        DOT8(t2, 16, s2);
        DOT8(t3, 24, s3);
        float s = (s0 + s1) + (s2 + s3);
        s += __shfl_xor(s, 1, 64);
        s += __shfl_xor(s, 2, 64);
        if (quarter == 0)
            out[OUT_LOGITS + (size_t)b * LL + half * 256 + grp + (e << 6)] = s;
    }
}

extern "C" void kernel_launch(void* const* d_in, const int* in_sizes, int n_in,
                              void* d_out, int out_size, void* d_ws, size_t ws_size,
                              hipStream_t stream) {
    const float* q     = (const float*)d_in[0];
    const float* queue = (const float*)d_in[1];
    const float* keys  = (const float*)d_in[2];
    const float* pq    = (const float*)d_in[3];
    const float* pk    = (const float*)d_in[4];
    const int*   sidx  = (const int*)d_in[5];
    const int*   ptr_p = (const int*)d_in[6];
    float* out = (float*)d_out;

    unsigned short* ws_qt = (unsigned short*)((char*)d_ws + WS_QT);

    // 1) ALL streaming: queue copy/overwrite + bf16 transpose + param update
    queue_param_kernel<<<2 * (KCOLS / 64), 256, 0, stream>>>(
        queue, keys, ptr_p, pq, pk, out, ws_qt);
    // 2) pure gather logits, 2 blocks per row
    logits_kernel<<<2 * BB, 256, 0, stream>>>(q, ws_qt, sidx,
                                              out + OUT_LOGITS);
}